// Round 8
// baseline (146.713 us; speedup 1.0000x reference)
//
#include <hip/hip_runtime.h>
#include <hip/hip_bf16.h>

typedef __attribute__((ext_vector_type(8))) short short8;   // bf16x8 MFMA operand
typedef __attribute__((ext_vector_type(4))) float floatx4;  // f32x4 MFMA accumulator

#define LOG2E 1.4426950408889634f

__device__ __forceinline__ unsigned short f2bf(float f) {
  unsigned int u = __float_as_uint(f);
  u += 0x7FFFu + ((u >> 16) & 1u);   // RNE
  return (unsigned short)(u >> 16);
}

__device__ __forceinline__ unsigned int pk2(float lo, float hi) {
  __hip_bfloat162 h = __float22bfloat162_rn(make_float2(lo, hi)); // v_cvt_pk_bf16_f32
  unsigned int u;
  __builtin_memcpy(&u, &h, 4);
  return u;
}

// ---------------- prep kernel (vectorized x4) ----------------
// ws layout (bytes):
//   Wp    [384][256] bf16 @ 0        (n' = d*64 + t, pre-scaled by -log2e)
//   fcw   [256][64]  bf16 @ 196608
//   coefg [64][64]   f32  @ 229376   (monomial-basis tree coeffs, BN folded)
//   b1t   [64][8]    f32  @ 245760   (tree-major, padded to 8)
//   to    [32768][64] bf16 @ 262144  (tree_out after BN)
__global__ void prep_kernel(const float* __restrict__ W_dec,
                            const float* __restrict__ b_dec,
                            const float* __restrict__ leaf,
                            const float* __restrict__ bn_gamma,
                            const float* __restrict__ bn_beta,
                            const float* __restrict__ bn_mean,
                            const float* __restrict__ bn_var,
                            const float* __restrict__ fc_w,
                            unsigned short* __restrict__ Wp,
                            unsigned short* __restrict__ fcw,
                            float* __restrict__ coefg,
                            float* __restrict__ b1t)
{
  int idx = (int)blockIdx.x * 256 + (int)threadIdx.x;
  if (idx < 24576) {                 // Wp: 4 k per thread
    int np = idx >> 6, k4 = (idx & 63) * 4;
    int d = np >> 6, t = np & 63;
    float4 v = *(const float4*)(W_dec + (size_t)(t * 6 + d) * 256 + k4);
    ushort4 r;
    r.x = f2bf(-LOG2E * v.x); r.y = f2bf(-LOG2E * v.y);
    r.z = f2bf(-LOG2E * v.z); r.w = f2bf(-LOG2E * v.w);
    *(ushort4*)(Wp + (size_t)np * 256 + k4) = r;
    return;
  }
  idx -= 24576;
  if (idx < 4096) {                  // fcw: 4 elems per thread
    float4 v = *(const float4*)(fc_w + idx * 4);
    ushort4 r;
    r.x = f2bf(v.x); r.y = f2bf(v.y); r.z = f2bf(v.z); r.w = f2bf(v.w);
    *(ushort4*)(fcw + idx * 4) = r;
    return;
  }
  idx -= 4096;
  if (idx < 64) {
    const int t = idx;
    float c[64];
    #pragma unroll
    for (int i = 0; i < 64; ++i) c[i] = leaf[t * 64 + i];
    #pragma unroll
    for (int p = 0; p < 6; ++p) {
      const int s = 1 << p;
      #pragma unroll
      for (int i = 0; i < 64; ++i)
        if ((i & s) == 0) c[i + s] -= c[i];
    }
    float sbv = bn_gamma[t] * rsqrtf(bn_var[t] + 1e-5f);
    float obv = bn_beta[t] - bn_mean[t] * sbv;
    #pragma unroll
    for (int i = 0; i < 64; ++i) c[i] *= sbv;
    c[0] += obv;
    #pragma unroll
    for (int i = 0; i < 64; ++i) coefg[t * 64 + i] = c[i];
    return;
  }
  idx -= 64;
  if (idx < 512) {
    int t = idx >> 3, d = idx & 7;
    b1t[idx] = (d < 6) ? (-LOG2E * b_dec[t * 6 + d]) : 0.0f;
  }
}

// ---------------- probe<LVL>: ablation ladder of the tree kernel ----------------
// LVL: 1=stage only | 6=stage+GEMM1(B loaded once) | 2=stage+GEMM1 |
//      3=+sigmoid | 4=+DP(no store) | 5=full (writes to)
template<int LVL>
__global__ __launch_bounds__(256, 3)
void probe(const float* __restrict__ x,
           const unsigned short* __restrict__ Wp,
           const float* __restrict__ coefg,
           const float* __restrict__ b1t,
           unsigned short* __restrict__ to)
{
  __shared__ unsigned short xbf[32][264];

  const int tid  = (int)threadIdx.x;
  const int lane = tid & 63;
  const int w    = tid >> 6;
  const int tcol = lane & 15;
  const int g    = lane >> 4;
  const int r0   = (int)blockIdx.x * 32;
  const int tree = w * 16 + tcol;

  const unsigned short* Bb = Wp + (size_t)tree * 256 + g * 8;
  short8 B[2][6];
  #pragma unroll
  for (int d = 0; d < 6; ++d) B[0][d] = *(const short8*)(Bb + d * 16384);

  // ---- stage x tile (32x256 f32, coalesced) -> bf16 ----
  {
    const float4* xs = (const float4*)(x + (size_t)r0 * 256);
    #pragma unroll
    for (int i = 0; i < 8; ++i) {
      int f = tid + 256 * i;
      float4 v = xs[f];
      int row = f >> 6, c4 = f & 63;
      unsigned int* p = (unsigned int*)&xbf[row][c4 * 4];
      p[0] = pk2(v.x, v.y);
      p[1] = pk2(v.z, v.w);
    }
  }
  __syncthreads();

  if constexpr (LVL == 1) {
    unsigned short v = xbf[lane & 31][(tid * 7) & 255];
    asm volatile("" :: "v"((int)v));
    return;
  }

  // ---- GEMM1 ----
  floatx4 acc[2][6];
  #pragma unroll
  for (int rt = 0; rt < 2; ++rt)
    #pragma unroll
    for (int d = 0; d < 6; ++d) { acc[rt][d][0]=0.f; acc[rt][d][1]=0.f; acc[rt][d][2]=0.f; acc[rt][d][3]=0.f; }

  #pragma unroll
  for (int kp = 0; kp < 8; ++kp) {
    if constexpr (LVL != 6) {
      if (kp < 7) {
        #pragma unroll
        for (int d = 0; d < 6; ++d)
          B[(kp + 1) & 1][d] = *(const short8*)(Bb + d * 16384 + (kp + 1) * 32);
      }
    }
    short8 a0 = *(const short8*)&xbf[tcol][kp * 32 + g * 8];
    short8 a1 = *(const short8*)&xbf[16 + tcol][kp * 32 + g * 8];
    #pragma unroll
    for (int d = 0; d < 6; ++d) {
      const short8 bf = (LVL == 6) ? B[0][d] : B[kp & 1][d];
      acc[0][d] = __builtin_amdgcn_mfma_f32_16x16x32_bf16(a0, bf, acc[0][d], 0, 0, 0);
      acc[1][d] = __builtin_amdgcn_mfma_f32_16x16x32_bf16(a1, bf, acc[1][d], 0, 0, 0);
    }
  }

  if constexpr (LVL == 2 || LVL == 6) {
    #pragma unroll
    for (int rt = 0; rt < 2; ++rt)
      #pragma unroll
      for (int d = 0; d < 6; ++d)
        #pragma unroll
        for (int j = 0; j < 4; ++j)
          asm volatile("" :: "v"(acc[rt][d][j]));
    return;
  }

  // ---- sigmoid ----
  float4 q0 = *(const float4*)(b1t + tree * 8);
  float4 q1 = *(const float4*)(b1t + tree * 8 + 4);
  float bp[6] = {q0.x, q0.y, q0.z, q0.w, q1.x, q1.y};
  #pragma unroll
  for (int rt = 0; rt < 2; ++rt)
    #pragma unroll
    for (int d = 0; d < 6; ++d)
      #pragma unroll
      for (int j = 0; j < 4; ++j) {
        float z = acc[rt][d][j] + bp[d];
        acc[rt][d][j] = __builtin_amdgcn_rcpf(1.0f + __builtin_amdgcn_exp2f(z));
      }

  if constexpr (LVL == 3) {
    #pragma unroll
    for (int rt = 0; rt < 2; ++rt)
      #pragma unroll
      for (int d = 0; d < 6; ++d)
        #pragma unroll
        for (int j = 0; j < 4; ++j)
          asm volatile("" :: "v"(acc[rt][d][j]));
    return;
  }

  // ---- tree DP (monomial basis, BN folded) ----
  const float* Ct = coefg + tree * 64;
  float4 lv[8];
  #pragma unroll
  for (int c = 0; c < 8; ++c) lv[c] = ((const float4*)Ct)[c];

  float L[32], resLo[8];
  #pragma unroll
  for (int c = 0; c < 8; ++c) {
    L[c*4+0] = lv[c].x; L[c*4+1] = lv[c].y; L[c*4+2] = lv[c].z; L[c*4+3] = lv[c].w;
  }
  float4 hv[8];
  #pragma unroll
  for (int c = 0; c < 8; ++c) hv[c] = ((const float4*)Ct)[8 + c];

  #pragma unroll
  for (int rt = 0; rt < 2; ++rt)
    #pragma unroll
    for (int j = 0; j < 4; ++j) {
      float u[16];
      const float d5 = acc[rt][5][j];
      #pragma unroll
      for (int i = 0; i < 16; ++i) u[i] = fmaf(d5, L[2*i+1], L[2*i]);
      const float d4 = acc[rt][4][j];
      #pragma unroll
      for (int i = 0; i < 8; ++i) u[i] = fmaf(d4, u[2*i+1], u[2*i]);
      const float d3 = acc[rt][3][j];
      #pragma unroll
      for (int i = 0; i < 4; ++i) u[i] = fmaf(d3, u[2*i+1], u[2*i]);
      const float d2 = acc[rt][2][j];
      #pragma unroll
      for (int i = 0; i < 2; ++i) u[i] = fmaf(d2, u[2*i+1], u[2*i]);
      resLo[rt*4+j] = fmaf(acc[rt][1][j], u[1], u[0]);
    }
  float tov[2][4];
  #pragma unroll
  for (int c = 0; c < 8; ++c) {
    L[c*4+0] = hv[c].x; L[c*4+1] = hv[c].y; L[c*4+2] = hv[c].z; L[c*4+3] = hv[c].w;
  }
  #pragma unroll
  for (int rt = 0; rt < 2; ++rt)
    #pragma unroll
    for (int j = 0; j < 4; ++j) {
      float u[16];
      const float d5 = acc[rt][5][j];
      #pragma unroll
      for (int i = 0; i < 16; ++i) u[i] = fmaf(d5, L[2*i+1], L[2*i]);
      const float d4 = acc[rt][4][j];
      #pragma unroll
      for (int i = 0; i < 8; ++i) u[i] = fmaf(d4, u[2*i+1], u[2*i]);
      const float d3 = acc[rt][3][j];
      #pragma unroll
      for (int i = 0; i < 4; ++i) u[i] = fmaf(d3, u[2*i+1], u[2*i]);
      const float d2 = acc[rt][2][j];
      #pragma unroll
      for (int i = 0; i < 2; ++i) u[i] = fmaf(d2, u[2*i+1], u[2*i]);
      float hi_r = fmaf(acc[rt][1][j], u[1], u[0]);
      tov[rt][j] = fmaf(acc[rt][0][j], hi_r, resLo[rt*4+j]);
    }

  if constexpr (LVL == 4) {
    #pragma unroll
    for (int rt = 0; rt < 2; ++rt)
      #pragma unroll
      for (int j = 0; j < 4; ++j)
        asm volatile("" :: "v"(tov[rt][j]));
    return;
  }

  // ---- LVL 5: store ----
  #pragma unroll
  for (int rt = 0; rt < 2; ++rt)
    #pragma unroll
    for (int j = 0; j < 4; ++j)
      to[(size_t)(r0 + rt * 16 + g * 4 + j) * 64 + tree] = f2bf(tov[rt][j]);
}

// ---------------- K2: out = to(32768x64) @ fcw^T + fc_b ----------------
__global__ __launch_bounds__(256, 2)
void node_fc(const unsigned short* __restrict__ to,
             const unsigned short* __restrict__ fcw,
             const float* __restrict__ fc_b,
             float* __restrict__ out)
{
  __shared__ unsigned short a2t[64][72];

  const int tid  = (int)threadIdx.x;
  const int lane = tid & 63;
  const int w    = tid >> 6;
  const int tcol = lane & 15;
  const int g    = lane >> 4;
  const int r0   = (int)blockIdx.x * 64;

  short8 B0[4], B1[4];
  float fcb[4];
  #pragma unroll
  for (int nt = 0; nt < 4; ++nt) {
    const unsigned short* p = fcw + (size_t)(w * 64 + nt * 16 + tcol) * 64 + g * 8;
    B0[nt] = *(const short8*)p;
    B1[nt] = *(const short8*)(p + 32);
    fcb[nt] = fc_b[w * 64 + nt * 16 + tcol];
  }

  {
    const short8* ts = (const short8*)(to + (size_t)r0 * 64);
    #pragma unroll
    for (int i = 0; i < 2; ++i) {
      int f = tid + 256 * i;
      int row = f >> 3, c8 = f & 7;
      *(short8*)&a2t[row][c8 * 8] = ts[f];
    }
  }
  __syncthreads();

  floatx4 acc[4][4];
  #pragma unroll
  for (int rt = 0; rt < 4; ++rt)
    #pragma unroll
    for (int nt = 0; nt < 4; ++nt) { acc[rt][nt][0]=0.f; acc[rt][nt][1]=0.f; acc[rt][nt][2]=0.f; acc[rt][nt][3]=0.f; }

  short8 a2[4];
  #pragma unroll
  for (int rt = 0; rt < 4; ++rt)
    a2[rt] = *(const short8*)&a2t[rt * 16 + tcol][g * 8];
  #pragma unroll
  for (int nt = 0; nt < 4; ++nt)
    #pragma unroll
    for (int rt = 0; rt < 4; ++rt)
      acc[rt][nt] = __builtin_amdgcn_mfma_f32_16x16x32_bf16(a2[rt], B0[nt], acc[rt][nt], 0, 0, 0);
  #pragma unroll
  for (int rt = 0; rt < 4; ++rt)
    a2[rt] = *(const short8*)&a2t[rt * 16 + tcol][32 + g * 8];
  #pragma unroll
  for (int nt = 0; nt < 4; ++nt)
    #pragma unroll
    for (int rt = 0; rt < 4; ++rt)
      acc[rt][nt] = __builtin_amdgcn_mfma_f32_16x16x32_bf16(a2[rt], B1[nt], acc[rt][nt], 0, 0, 0);

  #pragma unroll
  for (int nt = 0; nt < 4; ++nt) {
    const int col = w * 64 + nt * 16 + tcol;
    #pragma unroll
    for (int rt = 0; rt < 4; ++rt)
      #pragma unroll
      for (int j = 0; j < 4; ++j)
        out[(size_t)(r0 + rt * 16 + g * 4 + j) * 256 + col] = acc[rt][nt][j] + fcb[nt];
  }
}

extern "C" void kernel_launch(void* const* d_in, const int* in_sizes, int n_in,
                              void* d_out, int out_size, void* d_ws, size_t ws_size,
                              hipStream_t stream) {
  const float* x        = (const float*)d_in[0];
  const float* W_dec    = (const float*)d_in[1];
  const float* b_dec    = (const float*)d_in[2];
  const float* leaf     = (const float*)d_in[3];
  const float* bn_gamma = (const float*)d_in[4];
  const float* bn_beta  = (const float*)d_in[5];
  const float* bn_mean  = (const float*)d_in[6];
  const float* bn_var   = (const float*)d_in[7];
  const float* fc_w     = (const float*)d_in[8];
  const float* fc_b     = (const float*)d_in[9];
  float* out = (float*)d_out;

  char* ws = (char*)d_ws;
  unsigned short* Wp  = (unsigned short*)(ws);            // 196608 B
  unsigned short* fcw = (unsigned short*)(ws + 196608);   // 32768 B
  float* coefg = (float*)(ws + 229376);                   // 16384 B
  float* b1t   = (float*)(ws + 245760);                   // 2048 B
  unsigned short* to = (unsigned short*)(ws + 262144);    // 4194304 B

  prep_kernel<<<115, 256, 0, stream>>>(W_dec, b_dec, leaf, bn_gamma, bn_beta,
                                       bn_mean, bn_var, fc_w,
                                       Wp, fcw, coefg, b1t);
  // ablation ladder (diagnostic round; each dispatch gets its own counter row)
  probe<1><<<1024, 256, 0, stream>>>(x, Wp, coefg, b1t, to);
  probe<6><<<1024, 256, 0, stream>>>(x, Wp, coefg, b1t, to);
  probe<2><<<1024, 256, 0, stream>>>(x, Wp, coefg, b1t, to);
  probe<3><<<1024, 256, 0, stream>>>(x, Wp, coefg, b1t, to);
  probe<4><<<1024, 256, 0, stream>>>(x, Wp, coefg, b1t, to);
  probe<5><<<1024, 256, 0, stream>>>(x, Wp, coefg, b1t, to);   // the real one
  node_fc<<<512, 256, 0, stream>>>(to, fcw, fc_b, out);
}

// Round 9
// 50.245 us; speedup vs baseline: 2.9199x; 2.9199x over previous
//
#include <hip/hip_runtime.h>
#include <hip/hip_bf16.h>

typedef __attribute__((ext_vector_type(8))) short short8;   // bf16x8 MFMA operand
typedef __attribute__((ext_vector_type(4))) float floatx4;  // f32x4 MFMA accumulator

#define LOG2E 1.4426950408889634f

__device__ __forceinline__ unsigned short f2bf(float f) {
  unsigned int u = __float_as_uint(f);
  u += 0x7FFFu + ((u >> 16) & 1u);   // RNE
  return (unsigned short)(u >> 16);
}

__device__ __forceinline__ unsigned int pk2(float lo, float hi) {
  __hip_bfloat162 h = __float22bfloat162_rn(make_float2(lo, hi)); // v_cvt_pk_bf16_f32
  unsigned int u;
  __builtin_memcpy(&u, &h, 4);
  return u;
}

// ---------------- prep kernel (vectorized x4) ----------------
// ws layout (bytes):
//   Wp    [384][256] bf16 @ 0        (n' = d*64 + t, pre-scaled by -log2e)
//   fcw   [256][64]  bf16 @ 196608
//   coefg [64][64]   f32  @ 229376   (monomial-basis tree coeffs, BN folded)
//   b1t   [64][8]    f32  @ 245760   (tree-major, padded to 8)
//   to    [32768][64] bf16 @ 262144  (tree_out after BN)
__global__ void prep_kernel(const float* __restrict__ W_dec,
                            const float* __restrict__ b_dec,
                            const float* __restrict__ leaf,
                            const float* __restrict__ bn_gamma,
                            const float* __restrict__ bn_beta,
                            const float* __restrict__ bn_mean,
                            const float* __restrict__ bn_var,
                            const float* __restrict__ fc_w,
                            unsigned short* __restrict__ Wp,
                            unsigned short* __restrict__ fcw,
                            float* __restrict__ coefg,
                            float* __restrict__ b1t)
{
  int idx = (int)blockIdx.x * 256 + (int)threadIdx.x;
  if (idx < 24576) {                 // Wp: 4 k per thread
    int np = idx >> 6, k4 = (idx & 63) * 4;
    int d = np >> 6, t = np & 63;
    float4 v = *(const float4*)(W_dec + (size_t)(t * 6 + d) * 256 + k4);
    ushort4 r;
    r.x = f2bf(-LOG2E * v.x); r.y = f2bf(-LOG2E * v.y);
    r.z = f2bf(-LOG2E * v.z); r.w = f2bf(-LOG2E * v.w);
    *(ushort4*)(Wp + (size_t)np * 256 + k4) = r;
    return;
  }
  idx -= 24576;
  if (idx < 4096) {                  // fcw: 4 elems per thread
    float4 v = *(const float4*)(fc_w + idx * 4);
    ushort4 r;
    r.x = f2bf(v.x); r.y = f2bf(v.y); r.z = f2bf(v.z); r.w = f2bf(v.w);
    *(ushort4*)(fcw + idx * 4) = r;
    return;
  }
  idx -= 4096;
  if (idx < 64) {
    const int t = idx;
    float c[64];
    #pragma unroll
    for (int i = 0; i < 64; ++i) c[i] = leaf[t * 64 + i];
    #pragma unroll
    for (int p = 0; p < 6; ++p) {
      const int s = 1 << p;
      #pragma unroll
      for (int i = 0; i < 64; ++i)
        if ((i & s) == 0) c[i + s] -= c[i];
    }
    float sbv = bn_gamma[t] * rsqrtf(bn_var[t] + 1e-5f);
    float obv = bn_beta[t] - bn_mean[t] * sbv;
    #pragma unroll
    for (int i = 0; i < 64; ++i) c[i] *= sbv;
    c[0] += obv;
    #pragma unroll
    for (int i = 0; i < 64; ++i) coefg[t * 64 + i] = c[i];
    return;
  }
  idx -= 64;
  if (idx < 512) {
    int t = idx >> 3, d = idx & 7;
    b1t[idx] = (d < 6) ? (-LOG2E * b_dec[t * 6 + d]) : 0.0f;
  }
}

// ---------------- K1: GEMM1 + sigmoid + tree DP -> to (bf16 [32768][64]) ----------------
// grid 1024 x 256; BM=32; 4 waves; wave w owns trees [16w,16w+16).
// DP streams coefs from LDS in 32-coef bites (8x ds_read_b128 per 2-eval unit);
// peak live set ~95 regs -> no remat of L2 loads inside the fma chain.
__global__ __launch_bounds__(256, 3)
void node_tree(const float* __restrict__ x,
               const unsigned short* __restrict__ Wp,
               const float* __restrict__ coefg,
               const float* __restrict__ b1t,
               unsigned short* __restrict__ to)
{
  __shared__ unsigned short xbf[32][264];   // 16.9 KB
  __shared__ float coef_lds[64][68];        // 17.4 KB (+4 pad: 2-way banks + broadcast = free)

  const int tid  = (int)threadIdx.x;
  const int lane = tid & 63;
  const int w    = tid >> 6;
  const int tcol = lane & 15;
  const int g    = lane >> 4;
  const int r0   = (int)blockIdx.x * 32;
  const int tree = w * 16 + tcol;

  // prefetch kp=0 B-fragments before staging (L2 latency hides under HBM burst)
  const unsigned short* Bb = Wp + (size_t)tree * 256 + g * 8;
  short8 B[2][6];
  #pragma unroll
  for (int d = 0; d < 6; ++d) B[0][d] = *(const short8*)(Bb + d * 16384);

  // stage x tile (32x256 f32, coalesced) -> bf16
  {
    const float4* xs = (const float4*)(x + (size_t)r0 * 256);
    #pragma unroll
    for (int i = 0; i < 8; ++i) {
      int f = tid + 256 * i;            // float4 index 0..2047
      float4 v = xs[f];
      int row = f >> 6, c4 = f & 63;
      unsigned int* p = (unsigned int*)&xbf[row][c4 * 4];
      p[0] = pk2(v.x, v.y);
      p[1] = pk2(v.z, v.w);
    }
    // stage coef table (16 KB, L2-hot) -> LDS
    #pragma unroll
    for (int i = 0; i < 4; ++i) {
      int f = tid + 256 * i;            // float4 index 0..1023
      int t = f >> 4, c4 = f & 15;
      *(float4*)&coef_lds[t][c4 * 4] = ((const float4*)coefg)[f];
    }
  }
  __syncthreads();

  // GEMM1: 8 K-steps; 2-deep B ring keeps 6 L2 loads in flight under 12 MFMAs
  floatx4 acc[2][6];
  #pragma unroll
  for (int rt = 0; rt < 2; ++rt)
    #pragma unroll
    for (int d = 0; d < 6; ++d) { acc[rt][d][0]=0.f; acc[rt][d][1]=0.f; acc[rt][d][2]=0.f; acc[rt][d][3]=0.f; }

  #pragma unroll
  for (int kp = 0; kp < 8; ++kp) {
    if (kp < 7) {
      #pragma unroll
      for (int d = 0; d < 6; ++d)
        B[(kp + 1) & 1][d] = *(const short8*)(Bb + d * 16384 + (kp + 1) * 32);
    }
    short8 a0 = *(const short8*)&xbf[tcol][kp * 32 + g * 8];
    short8 a1 = *(const short8*)&xbf[16 + tcol][kp * 32 + g * 8];
    #pragma unroll
    for (int d = 0; d < 6; ++d) {
      acc[0][d] = __builtin_amdgcn_mfma_f32_16x16x32_bf16(a0, B[kp & 1][d], acc[0][d], 0, 0, 0);
      acc[1][d] = __builtin_amdgcn_mfma_f32_16x16x32_bf16(a1, B[kp & 1][d], acc[1][d], 0, 0, 0);
    }
  }

  // sigmoid (dec values), b1 from L2 (hidden under trans burst)
  float4 q0 = *(const float4*)(b1t + tree * 8);
  float4 q1 = *(const float4*)(b1t + tree * 8 + 4);
  float bp[6] = {q0.x, q0.y, q0.z, q0.w, q1.x, q1.y};
  #pragma unroll
  for (int rt = 0; rt < 2; ++rt)
    #pragma unroll
    for (int d = 0; d < 6; ++d)
      #pragma unroll
      for (int j = 0; j < 4; ++j) {
        float z = acc[rt][d][j] + bp[d];
        acc[rt][d][j] = __builtin_amdgcn_rcpf(1.0f + __builtin_amdgcn_exp2f(z));
      }

  // ---- tree DP: (rt x j-pair x half) units; 8x ds_read_b128 + 62 fma per unit ----
  const float* Crow = &coef_lds[tree][0];
  float res[2][4];
  #pragma unroll
  for (int rt = 0; rt < 2; ++rt) {
    #pragma unroll
    for (int jp = 0; jp < 2; ++jp) {
      const int j0 = 2 * jp, j1 = 2 * jp + 1;
      const float a5 = acc[rt][5][j0], b5 = acc[rt][5][j1];
      const float a4 = acc[rt][4][j0], b4 = acc[rt][4][j1];
      const float a3 = acc[rt][3][j0], b3 = acc[rt][3][j1];
      const float a2 = acc[rt][2][j0], b2 = acc[rt][2][j1];
      const float a1 = acc[rt][1][j0], b1 = acc[rt][1][j1];
      float hv0[2], hv1[2];                 // [half] per eval
      #pragma unroll
      for (int h = 0; h < 2; ++h) {
        float u0[16], u1[16];
        #pragma unroll
        for (int c = 0; c < 8; ++c) {
          float4 v = *(const float4*)(Crow + h * 32 + c * 4);   // ds_read_b128
          u0[2*c]   = fmaf(a5, v.y, v.x);
          u0[2*c+1] = fmaf(a5, v.w, v.z);
          u1[2*c]   = fmaf(b5, v.y, v.x);
          u1[2*c+1] = fmaf(b5, v.w, v.z);
        }
        #pragma unroll
        for (int i = 0; i < 8; ++i) { u0[i] = fmaf(a4, u0[2*i+1], u0[2*i]); u1[i] = fmaf(b4, u1[2*i+1], u1[2*i]); }
        #pragma unroll
        for (int i = 0; i < 4; ++i) { u0[i] = fmaf(a3, u0[2*i+1], u0[2*i]); u1[i] = fmaf(b3, u1[2*i+1], u1[2*i]); }
        #pragma unroll
        for (int i = 0; i < 2; ++i) { u0[i] = fmaf(a2, u0[2*i+1], u0[2*i]); u1[i] = fmaf(b2, u1[2*i+1], u1[2*i]); }
        hv0[h] = fmaf(a1, u0[1], u0[0]);
        hv1[h] = fmaf(b1, u1[1], u1[0]);
      }
      res[rt][j0] = fmaf(acc[rt][0][j0], hv0[1], hv0[0]);
      res[rt][j1] = fmaf(acc[rt][0][j1], hv1[1], hv1[0]);
    }
  }

  // store tree_out (bf16)
  #pragma unroll
  for (int rt = 0; rt < 2; ++rt)
    #pragma unroll
    for (int j = 0; j < 4; ++j)
      to[(size_t)(r0 + rt * 16 + g * 4 + j) * 64 + tree] = f2bf(res[rt][j]);
}

// ---------------- K2: out = to(32768x64) @ fcw^T + fc_b ----------------
__global__ __launch_bounds__(256, 2)
void node_fc(const unsigned short* __restrict__ to,
             const unsigned short* __restrict__ fcw,
             const float* __restrict__ fc_b,
             float* __restrict__ out)
{
  __shared__ unsigned short a2t[64][72];

  const int tid  = (int)threadIdx.x;
  const int lane = tid & 63;
  const int w    = tid >> 6;
  const int tcol = lane & 15;
  const int g    = lane >> 4;
  const int r0   = (int)blockIdx.x * 64;

  short8 B0[4], B1[4];
  float fcb[4];
  #pragma unroll
  for (int nt = 0; nt < 4; ++nt) {
    const unsigned short* p = fcw + (size_t)(w * 64 + nt * 16 + tcol) * 64 + g * 8;
    B0[nt] = *(const short8*)p;
    B1[nt] = *(const short8*)(p + 32);
    fcb[nt] = fc_b[w * 64 + nt * 16 + tcol];
  }

  {
    const short8* ts = (const short8*)(to + (size_t)r0 * 64);
    #pragma unroll
    for (int i = 0; i < 2; ++i) {
      int f = tid + 256 * i;
      int row = f >> 3, c8 = f & 7;
      *(short8*)&a2t[row][c8 * 8] = ts[f];
    }
  }
  __syncthreads();

  floatx4 acc[4][4];
  #pragma unroll
  for (int rt = 0; rt < 4; ++rt)
    #pragma unroll
    for (int nt = 0; nt < 4; ++nt) { acc[rt][nt][0]=0.f; acc[rt][nt][1]=0.f; acc[rt][nt][2]=0.f; acc[rt][nt][3]=0.f; }

  short8 a2[4];
  #pragma unroll
  for (int rt = 0; rt < 4; ++rt)
    a2[rt] = *(const short8*)&a2t[rt * 16 + tcol][g * 8];
  #pragma unroll
  for (int nt = 0; nt < 4; ++nt)
    #pragma unroll
    for (int rt = 0; rt < 4; ++rt)
      acc[rt][nt] = __builtin_amdgcn_mfma_f32_16x16x32_bf16(a2[rt], B0[nt], acc[rt][nt], 0, 0, 0);
  #pragma unroll
  for (int rt = 0; rt < 4; ++rt)
    a2[rt] = *(const short8*)&a2t[rt * 16 + tcol][32 + g * 8];
  #pragma unroll
  for (int nt = 0; nt < 4; ++nt)
    #pragma unroll
    for (int rt = 0; rt < 4; ++rt)
      acc[rt][nt] = __builtin_amdgcn_mfma_f32_16x16x32_bf16(a2[rt], B1[nt], acc[rt][nt], 0, 0, 0);

  #pragma unroll
  for (int nt = 0; nt < 4; ++nt) {
    const int col = w * 64 + nt * 16 + tcol;
    #pragma unroll
    for (int rt = 0; rt < 4; ++rt)
      #pragma unroll
      for (int j = 0; j < 4; ++j)
        out[(size_t)(r0 + rt * 16 + g * 4 + j) * 256 + col] = acc[rt][nt][j] + fcb[nt];
  }
}

extern "C" void kernel_launch(void* const* d_in, const int* in_sizes, int n_in,
                              void* d_out, int out_size, void* d_ws, size_t ws_size,
                              hipStream_t stream) {
  const float* x        = (const float*)d_in[0];
  const float* W_dec    = (const float*)d_in[1];
  const float* b_dec    = (const float*)d_in[2];
  const float* leaf     = (const float*)d_in[3];
  const float* bn_gamma = (const float*)d_in[4];
  const float* bn_beta  = (const float*)d_in[5];
  const float* bn_mean  = (const float*)d_in[6];
  const float* bn_var   = (const float*)d_in[7];
  const float* fc_w     = (const float*)d_in[8];
  const float* fc_b     = (const float*)d_in[9];
  float* out = (float*)d_out;

  char* ws = (char*)d_ws;
  unsigned short* Wp  = (unsigned short*)(ws);            // 196608 B
  unsigned short* fcw = (unsigned short*)(ws + 196608);   // 32768 B
  float* coefg = (float*)(ws + 229376);                   // 16384 B
  float* b1t   = (float*)(ws + 245760);                   // 2048 B
  unsigned short* to = (unsigned short*)(ws + 262144);    // 4194304 B

  prep_kernel<<<115, 256, 0, stream>>>(W_dec, b_dec, leaf, bn_gamma, bn_beta,
                                       bn_mean, bn_var, fc_w,
                                       Wp, fcw, coefg, b1t);
  node_tree<<<1024, 256, 0, stream>>>(x, Wp, coefg, b1t, to);
  node_fc<<<512, 256, 0, stream>>>(to, fcw, fc_b, out);
}